// Round 1
// baseline (417.587 us; speedup 1.0000x reference)
//
#include <hip/hip_runtime.h>
#include <hip/hip_bf16.h>
#include <math.h>

#define N_VOX 4096
#define C_IN  128

// ---------------------------------------------------------------------------
// Kernel 1: q/k/v projections (1x1x1 conv == per-voxel linear over channels)
// ws layout (floats): q[B][16][N] at 0, k[B][16][N] at 131072, v[B][128][N] at 262144
// ---------------------------------------------------------------------------
__global__ __launch_bounds__(256) void proj_kernel(
    const float* __restrict__ x,
    const float* __restrict__ wq, const float* __restrict__ bq,
    const float* __restrict__ wk, const float* __restrict__ bk,
    const float* __restrict__ wv, const float* __restrict__ bv,
    float* __restrict__ ws) {
  const int N = N_VOX, C = C_IN;
  int t   = threadIdx.x;
  int bid = blockIdx.x;            // grid = 2 * 20 * 16 = 640
  int b   = bid / 320;
  int rem = bid % 320;
  int og  = rem >> 4;              // 0..19 : group of 8 output rows
  int nb  = rem & 15;
  int n   = nb * 256 + t;
  int o0  = og * 8;

  float* wsq = ws;
  float* wsk = ws + 2 * 16 * N_VOX;
  float* wsv = ws + 4 * 16 * N_VOX;

  const float* wrow[8];
  float*       dst[8];
  float        acc[8];
#pragma unroll
  for (int oo = 0; oo < 8; ++oo) {
    int o = o0 + oo;
    if (o < 16) {
      wrow[oo] = wq + o * C;        acc[oo] = bq[o];
      dst[oo]  = wsq + (size_t)(b * 16 + o) * N;
    } else if (o < 32) {
      wrow[oo] = wk + (o - 16) * C; acc[oo] = bk[o - 16];
      dst[oo]  = wsk + (size_t)(b * 16 + (o - 16)) * N;
    } else {
      wrow[oo] = wv + (o - 32) * C; acc[oo] = bv[o - 32];
      dst[oo]  = wsv + (size_t)(b * 128 + (o - 32)) * N;
    }
  }

  const float* xp = x + (size_t)b * C * N + n;
#pragma unroll 4
  for (int c = 0; c < C; ++c) {
    float xv = xp[(size_t)c * N];
#pragma unroll
    for (int oo = 0; oo < 8; ++oo) acc[oo] = fmaf(wrow[oo][c], xv, acc[oo]);
  }
#pragma unroll
  for (int oo = 0; oo < 8; ++oo) dst[oo][n] = acc[oo];
}

// ---------------------------------------------------------------------------
// Kernel 2: fused flash attention + gamma*out + x
// One block per (batch, 32-query tile). 256 threads. 64-key tiles.
// ---------------------------------------------------------------------------
__global__ __launch_bounds__(256) void attn_kernel(
    const float* __restrict__ ws,
    const float* __restrict__ x,
    const float* __restrict__ gamma_p,
    float* __restrict__ out) {
  const int N = N_VOX;

  __shared__ float ks[64 * 20];    // k tile, [j][c] pad 20   (5.0 KB)
  __shared__ float vs[64 * 132];   // v tile, [j][c] pad 132  (33.8 KB) ; reused as o_s[c][q] pad 33
  __shared__ float ps[64 * 34];    // p tile, [j][q] pad 34   (8.5 KB)
  __shared__ float qs[32 * 17];    // q tile, [q][c] pad 17   (2.1 KB)
  __shared__ float m_s[32], l_s[32], scale_s[32];

  int t   = threadIdx.x;
  int bid = blockIdx.x;            // grid = 2 * 128 = 256
  int b   = bid >> 7;
  int i0  = (bid & 127) * 32;

  const float* q = ws;
  const float* k = ws + 2 * 16 * N;
  const float* v = ws + 4 * 16 * N;

  // stage q for this block's 32 queries
  for (int idx = t; idx < 32 * 16; idx += 256) {
    int qq = idx >> 4, c = idx & 15;
    qs[qq * 17 + c] = q[(size_t)(b * 16 + c) * N + i0 + qq];
  }
  if (t < 32) { m_s[t] = -1e30f; l_s[t] = 0.f; }

  // S-phase ids: 8 lanes per query
  int qi = t >> 3, sub = t & 7;
  // PV-phase ids: 2 queries x 8 channels per thread
  int tq = t >> 4, tc = t & 15;
  int q0 = tq * 2, c0 = tc * 8;

  float acc[2][8];
#pragma unroll
  for (int a = 0; a < 2; ++a)
#pragma unroll
    for (int d = 0; d < 8; ++d) acc[a][d] = 0.f;

  __syncthreads();
  float qreg[16];
#pragma unroll
  for (int c = 0; c < 16; ++c) qreg[c] = qs[qi * 17 + c];

  for (int tile = 0; tile < N / 64; ++tile) {
    const int j0 = tile * 64;
    __syncthreads();  // prior PV reads of vs/ps complete

    // stage k tile transposed: ks[j][c]
    for (int idx = t; idx < 16 * 64; idx += 256) {
      int c = idx >> 6, j = idx & 63;
      ks[j * 20 + c] = k[(size_t)(b * 16 + c) * N + j0 + j];
    }
    // stage v tile transposed: vs[j][c]
    for (int idx = t; idx < 128 * 64; idx += 256) {
      int c = idx >> 6, j = idx & 63;
      vs[j * 132 + c] = v[(size_t)(b * 128 + c) * N + j0 + j];
    }
    __syncthreads();

    // ---- S phase: each thread computes s for 8 j's of its query ----
    float s[8];
#pragma unroll
    for (int jj = 0; jj < 8; ++jj) {
      int j = sub + jj * 8;
      const float4* kp = reinterpret_cast<const float4*>(&ks[j * 20]);
      float4 k0 = kp[0], k1 = kp[1], k2 = kp[2], k3 = kp[3];
      float sa = 0.f;
      sa = fmaf(qreg[0],  k0.x, sa); sa = fmaf(qreg[1],  k0.y, sa);
      sa = fmaf(qreg[2],  k0.z, sa); sa = fmaf(qreg[3],  k0.w, sa);
      sa = fmaf(qreg[4],  k1.x, sa); sa = fmaf(qreg[5],  k1.y, sa);
      sa = fmaf(qreg[6],  k1.z, sa); sa = fmaf(qreg[7],  k1.w, sa);
      sa = fmaf(qreg[8],  k2.x, sa); sa = fmaf(qreg[9],  k2.y, sa);
      sa = fmaf(qreg[10], k2.z, sa); sa = fmaf(qreg[11], k2.w, sa);
      sa = fmaf(qreg[12], k3.x, sa); sa = fmaf(qreg[13], k3.y, sa);
      sa = fmaf(qreg[14], k3.z, sa); sa = fmaf(qreg[15], k3.w, sa);
      s[jj] = sa;
    }
    // tile max over the 64 j's of this query (8 local + 8-lane reduce)
    float tmax = s[0];
#pragma unroll
    for (int jj = 1; jj < 8; ++jj) tmax = fmaxf(tmax, s[jj]);
    tmax = fmaxf(tmax, __shfl_xor(tmax, 1));
    tmax = fmaxf(tmax, __shfl_xor(tmax, 2));
    tmax = fmaxf(tmax, __shfl_xor(tmax, 4));

    float m_old = m_s[qi];
    float m_new = fmaxf(m_old, tmax);
    float psum = 0.f;
#pragma unroll
    for (int jj = 0; jj < 8; ++jj) {
      float p = __expf(s[jj] - m_new);
      ps[(sub + 8 * jj) * 34 + qi] = p;
      psum += p;
    }
    psum += __shfl_xor(psum, 1);
    psum += __shfl_xor(psum, 2);
    psum += __shfl_xor(psum, 4);
    if (sub == 0) {
      float sc = __expf(m_old - m_new);
      scale_s[qi] = sc;
      l_s[qi] = l_s[qi] * sc + psum;
      m_s[qi] = m_new;
    }
    __syncthreads();

    // ---- PV phase: acc[2 queries][8 channels] ----
    float sc0 = scale_s[q0], sc1 = scale_s[q0 + 1];
#pragma unroll
    for (int d = 0; d < 8; ++d) { acc[0][d] *= sc0; acc[1][d] *= sc1; }
#pragma unroll 4
    for (int j = 0; j < 64; ++j) {
      const float2 pp = *reinterpret_cast<const float2*>(&ps[j * 34 + q0]);
      const float4 va = *reinterpret_cast<const float4*>(&vs[j * 132 + c0]);
      const float4 vb = *reinterpret_cast<const float4*>(&vs[j * 132 + c0 + 4]);
      acc[0][0] = fmaf(pp.x, va.x, acc[0][0]);
      acc[0][1] = fmaf(pp.x, va.y, acc[0][1]);
      acc[0][2] = fmaf(pp.x, va.z, acc[0][2]);
      acc[0][3] = fmaf(pp.x, va.w, acc[0][3]);
      acc[0][4] = fmaf(pp.x, vb.x, acc[0][4]);
      acc[0][5] = fmaf(pp.x, vb.y, acc[0][5]);
      acc[0][6] = fmaf(pp.x, vb.z, acc[0][6]);
      acc[0][7] = fmaf(pp.x, vb.w, acc[0][7]);
      acc[1][0] = fmaf(pp.y, va.x, acc[1][0]);
      acc[1][1] = fmaf(pp.y, va.y, acc[1][1]);
      acc[1][2] = fmaf(pp.y, va.z, acc[1][2]);
      acc[1][3] = fmaf(pp.y, va.w, acc[1][3]);
      acc[1][4] = fmaf(pp.y, vb.x, acc[1][4]);
      acc[1][5] = fmaf(pp.y, vb.y, acc[1][5]);
      acc[1][6] = fmaf(pp.y, vb.z, acc[1][6]);
      acc[1][7] = fmaf(pp.y, vb.w, acc[1][7]);
    }
  }

  // ---- epilogue: transpose through LDS (reuse vs), coalesced store ----
  __syncthreads();
#pragma unroll
  for (int a = 0; a < 2; ++a)
#pragma unroll
    for (int d = 0; d < 8; ++d) vs[(c0 + d) * 33 + (q0 + a)] = acc[a][d];
  __syncthreads();

  float g0 = gamma_p[0];
  for (int idx = t; idx < 128 * 32; idx += 256) {
    int c = idx >> 5, qq = idx & 31;
    float o = vs[c * 33 + qq] / l_s[qq];
    size_t addr = (size_t)(b * 128 + c) * N + i0 + qq;
    out[addr] = fmaf(g0, o, x[addr]);
  }
}

// ---------------------------------------------------------------------------
extern "C" void kernel_launch(void* const* d_in, const int* in_sizes, int n_in,
                              void* d_out, int out_size, void* d_ws, size_t ws_size,
                              hipStream_t stream) {
  const float* x     = (const float*)d_in[0];
  const float* wq    = (const float*)d_in[1];
  const float* bq    = (const float*)d_in[2];
  const float* wk    = (const float*)d_in[3];
  const float* bk    = (const float*)d_in[4];
  const float* wv    = (const float*)d_in[5];
  const float* bv    = (const float*)d_in[6];
  const float* gamma = (const float*)d_in[7];
  float* out = (float*)d_out;
  float* ws  = (float*)d_ws;   // needs 1,310,720 floats = 5.25 MB

  proj_kernel<<<640, 256, 0, stream>>>(x, wq, bq, wk, bk, wv, bv, ws);
  attn_kernel<<<256, 256, 0, stream>>>(ws, x, gamma, out);
}

// Round 2
// 104.911 us; speedup vs baseline: 3.9804x; 3.9804x over previous
//
#include <hip/hip_runtime.h>
#include <hip/hip_bf16.h>
#include <math.h>

#define N_VOX 4096
#define C_IN  128

typedef __bf16 bf16x8 __attribute__((ext_vector_type(8)));
typedef __bf16 bf16x4 __attribute__((ext_vector_type(4)));
typedef float f32x4 __attribute__((ext_vector_type(4)));

// ws layout (bf16 elements):
//   qt[b][n][32]  @ 0        (rows zero-padded 16..31)   2*4096*32 = 262144
//   kt[b][n][32]  @ 262144   (rows zero-padded 16..31)   262144
//   v [b][c][n]   @ 524288                               2*128*4096 = 1048576
// total 1,572,864 bf16 = 3 MB

// ---------------------------------------------------------------------------
// Kernel 1: q/k/v projections -> bf16, layouts for MFMA fragment loads
// ---------------------------------------------------------------------------
__global__ __launch_bounds__(256) void proj_kernel(
    const float* __restrict__ x,
    const float* __restrict__ wq, const float* __restrict__ bq,
    const float* __restrict__ wk, const float* __restrict__ bk,
    const float* __restrict__ wv, const float* __restrict__ bv,
    __bf16* __restrict__ ws) {
  const int N = N_VOX, C = C_IN;
  int t   = threadIdx.x;
  int bid = blockIdx.x;            // grid = 2 * 20 * 16 = 640
  int b   = bid / 320;
  int rem = bid % 320;
  int og  = rem >> 4;              // 0..19 : group of 8 output rows
  int nb  = rem & 15;
  int n   = nb * 256 + t;
  int o0  = og * 8;

  __bf16* qt = ws;
  __bf16* kt = ws + 262144;
  __bf16* vt = ws + 524288;

  const float* wrow[8];
  float        acc[8];
#pragma unroll
  for (int oo = 0; oo < 8; ++oo) {
    int o = o0 + oo;
    if (o < 16)      { wrow[oo] = wq + o * C;        acc[oo] = bq[o]; }
    else if (o < 32) { wrow[oo] = wk + (o - 16) * C; acc[oo] = bk[o - 16]; }
    else             { wrow[oo] = wv + (o - 32) * C; acc[oo] = bv[o - 32]; }
  }

  const float* xp = x + (size_t)b * C * N + n;
#pragma unroll 4
  for (int c = 0; c < C; ++c) {
    float xv = xp[(size_t)c * N];
#pragma unroll
    for (int oo = 0; oo < 8; ++oo) acc[oo] = fmaf(wrow[oo][c], xv, acc[oo]);
  }

  if (o0 < 32) {
    // q or k: 8 consecutive channels of one transposed row -> one 16B store,
    // plus a 16B zero store covering half of the 16..31 pad.
    union { __bf16 h[8]; uint4 u; } pk;
#pragma unroll
    for (int oo = 0; oo < 8; ++oo) pk.h[oo] = (__bf16)acc[oo];
    __bf16* base = (o0 < 16) ? qt : kt;
    int oo0 = o0 & 15;                      // 0 or 8
    size_t roff = (size_t)(b * 4096 + n) * 32;
    *reinterpret_cast<uint4*>(base + roff + oo0) = pk.u;
    uint4 z = {0u, 0u, 0u, 0u};
    *reinterpret_cast<uint4*>(base + roff + 16 + oo0) = z;
  } else {
#pragma unroll
    for (int oo = 0; oo < 8; ++oo)
      vt[(size_t)(b * 128 + (o0 - 32) + oo) * N + n] = (__bf16)acc[oo];
  }
}

// ---------------------------------------------------------------------------
// Kernel 2: fused flash attention (bf16 MFMA) + gamma*out + x
// grid = 512 : (b, 16-query tile). 4 waves/block, each wave = 1024 keys.
// ---------------------------------------------------------------------------
__global__ __launch_bounds__(256) void attn_kernel(
    const __bf16* __restrict__ ws,
    const float* __restrict__ x,
    const float* __restrict__ gamma_p,
    float* __restrict__ out) {
  __shared__ __align__(16) ushort ps_raw[4][16 * 72];  // per-wave P, row pad 72
  __shared__ float o_lds[128][17];
  __shared__ float m_lds[4][16], l_lds[4][16], lstar_lds[16];

  const int t    = threadIdx.x;
  const int w    = t >> 6;         // wave 0..3
  const int lane = t & 63;
  const int cq   = lane & 15;      // q-column (QK^T D) / c-row (PV A/D)
  const int g    = lane >> 4;      // lane group 0..3
  const int g8   = g * 8;
  const int g4   = g * 4;

  const int bid = blockIdx.x;      // 512
  const int b   = bid >> 8;
  const int qt0 = (bid & 255) * 16;

  const __bf16* qt = ws;
  const __bf16* kt = ws + 262144;
  const __bf16* vt = ws + 524288;

  // Q B-fragment (hoisted): B[k=c][col=q], rows zero-padded so no branch
  bf16x8 qfrag = *reinterpret_cast<const bf16x8*>(
      qt + (size_t)(b * 4096 + qt0 + cq) * 32 + g8);

  f32x4 acc[8];
  const f32x4 zero4 = {0.f, 0.f, 0.f, 0.f};
#pragma unroll
  for (int ct = 0; ct < 8; ++ct) acc[ct] = zero4;
  float m = -1e30f, l = 0.f;

  __bf16* psw = reinterpret_cast<__bf16*>(&ps_raw[w][0]) + cq * 72;

  const int j_base = w * 1024;
  for (int tile = 0; tile < 16; ++tile) {
    const int j0 = j_base + tile * 64;

    // ---- QK^T: S^T[j][q] over 4 j-subtiles of 16 ----
    f32x4 sf[4];
#pragma unroll
    for (int s = 0; s < 4; ++s) {
      bf16x8 kfrag = *reinterpret_cast<const bf16x8*>(
          kt + (size_t)(b * 4096 + j0 + s * 16 + cq) * 32 + g8);
      sf[s] = __builtin_amdgcn_mfma_f32_16x16x32_bf16(kfrag, qfrag, zero4, 0, 0, 0);
    }

    // ---- online softmax (per lane: 16 s-values for q=cq, j=s*16+g*4+v) ----
    float tmax = sf[0][0];
#pragma unroll
    for (int s = 0; s < 4; ++s)
#pragma unroll
      for (int v = 0; v < 4; ++v) tmax = fmaxf(tmax, sf[s][v]);
    tmax = fmaxf(tmax, __shfl_xor(tmax, 16));
    tmax = fmaxf(tmax, __shfl_xor(tmax, 32));

    if (!__all(tmax <= m + 8.0f)) {           // defer-max (T13)
      float m_new = fmaxf(m, tmax);
      float sc = __expf(m - m_new);
#pragma unroll
      for (int ct = 0; ct < 8; ++ct) acc[ct] *= sc;
      l *= sc;
      m = m_new;
    }

    float psum = 0.f;
#pragma unroll
    for (int s = 0; s < 4; ++s) {
      bf16x4 pk;
#pragma unroll
      for (int v = 0; v < 4; ++v) {
        float p = __expf(sf[s][v] - m);
        psum += p;
        pk[v] = (__bf16)p;
      }
      *reinterpret_cast<bf16x4*>(psw + s * 16 + g4) = pk;  // 8B LDS store
    }
    psum += __shfl_xor(psum, 16);
    psum += __shfl_xor(psum, 32);
    l += psum;

    // ---- PV: O^T[c][q] += V^T[c][j] * P^T[j][q], two 32-j chunks ----
#pragma unroll
    for (int cn = 0; cn < 2; ++cn) {
      bf16x8 pfrag = *reinterpret_cast<const bf16x8*>(psw + cn * 32 + g8);
      const __bf16* vb = vt + (size_t)(b * 128 + cq) * 4096 + j0 + cn * 32 + g8;
#pragma unroll
      for (int ct = 0; ct < 8; ++ct) {
        bf16x8 vfrag = *reinterpret_cast<const bf16x8*>(vb + (size_t)ct * 16 * 4096);
        acc[ct] = __builtin_amdgcn_mfma_f32_16x16x32_bf16(vfrag, pfrag, acc[ct], 0, 0, 0);
      }
    }
  }

  // ---- cross-wave merge (online-softmax merge of 4 partials) ----
  if (lane < 16) { m_lds[w][lane] = m; l_lds[w][lane] = l; }
  __syncthreads();

  float mstar = fmaxf(fmaxf(m_lds[0][cq], m_lds[1][cq]),
                      fmaxf(m_lds[2][cq], m_lds[3][cq]));
  float lstar = 0.f;
#pragma unroll
  for (int ww = 0; ww < 4; ++ww)
    lstar += l_lds[ww][cq] * __expf(m_lds[ww][cq] - mstar);
  float myscale = __expf(m - mstar);
  if (w == 0 && lane < 16) lstar_lds[lane] = lstar;

#pragma unroll
  for (int ww = 0; ww < 4; ++ww) {
    if (w == ww) {
#pragma unroll
      for (int ct = 0; ct < 8; ++ct)
#pragma unroll
        for (int v = 0; v < 4; ++v) {
          float val = acc[ct][v] * myscale;
          int c = ct * 16 + g4 + v;
          if (ww == 0) o_lds[c][cq] = val;
          else         o_lds[c][cq] += val;
        }
    }
    __syncthreads();
  }

  // ---- epilogue: out = gamma * O/l + x ----
  const float g0 = gamma_p[0];
  for (int idx = t; idx < 128 * 16; idx += 256) {
    int c = idx >> 4, qq = idx & 15;
    float o = o_lds[c][qq] / lstar_lds[qq];
    size_t addr = (size_t)(b * 128 + c) * N_VOX + qt0 + qq;
    out[addr] = fmaf(g0, o, x[addr]);
  }
}

// ---------------------------------------------------------------------------
extern "C" void kernel_launch(void* const* d_in, const int* in_sizes, int n_in,
                              void* d_out, int out_size, void* d_ws, size_t ws_size,
                              hipStream_t stream) {
  const float* x     = (const float*)d_in[0];
  const float* wq    = (const float*)d_in[1];
  const float* bq    = (const float*)d_in[2];
  const float* wk    = (const float*)d_in[3];
  const float* bk    = (const float*)d_in[4];
  const float* wv    = (const float*)d_in[5];
  const float* bv    = (const float*)d_in[6];
  const float* gamma = (const float*)d_in[7];
  float* out = (float*)d_out;
  __bf16* ws = (__bf16*)d_ws;   // needs 3 MB

  proj_kernel<<<640, 256, 0, stream>>>(x, wq, bq, wk, bk, wv, bv, ws);
  attn_kernel<<<512, 256, 0, stream>>>(ws, x, gamma, out);
}

// Round 3
// 86.071 us; speedup vs baseline: 4.8516x; 1.2189x over previous
//
#include <hip/hip_runtime.h>
#include <hip/hip_bf16.h>
#include <math.h>

#define N_VOX 4096

typedef __bf16 bf16x8 __attribute__((ext_vector_type(8)));
typedef __bf16 bf16x4 __attribute__((ext_vector_type(4)));
typedef float f32x4 __attribute__((ext_vector_type(4)));

// ws layout (bf16 elements):
//   qt[b][n][32]  @ 0        (rows zero-padded 16..31)   262144
//   kt[b][n][32]  @ 262144                               262144
//   v [b][c][n]   @ 524288                               1048576
// total 3 MB

// ---------------------------------------------------------------------------
// Kernel 1: q/k/v projections as MFMA GEMM.
// grid = 2b x 64 ntiles = 128 blocks, 256 threads (4 waves).
// Block: stage x[c][n0..n0+64] transposed+bf16 into LDS, then each wave
// computes o-tiles {w, w+4, w+8} of the 10 16-row output tiles
// (tile 0 = q, 1 = k, 2..9 = v rows 16*(ot-2)..).
// ---------------------------------------------------------------------------
__global__ __launch_bounds__(256) void proj_kernel(
    const float* __restrict__ x,
    const float* __restrict__ wq, const float* __restrict__ bq,
    const float* __restrict__ wk, const float* __restrict__ bk,
    const float* __restrict__ wv, const float* __restrict__ bv,
    __bf16* __restrict__ ws) {
  __shared__ __bf16 xs[64 * 136];   // [n][c], row stride 136 (16B-aligned rows)

  const int t   = threadIdx.x;
  const int bid = blockIdx.x;       // 128 = 2 * 64
  const int b   = bid >> 6;
  const int n0  = (bid & 63) * 64;

  for (int idx = t; idx < 128 * 64; idx += 256) {
    int c = idx >> 6, n = idx & 63;
    xs[n * 136 + c] = (__bf16)x[(size_t)(b * 128 + c) * N_VOX + n0 + n];
  }
  __syncthreads();

  const int w = t >> 6, lane = t & 63;
  const int cq = lane & 15, g = lane >> 4, g8 = g * 8, g4 = g * 4;

  __bf16* qt = ws;
  __bf16* kt = ws + 262144;
  __bf16* vt = ws + 524288;
  const f32x4 zero4 = {0.f, 0.f, 0.f, 0.f};

  for (int ot = w; ot < 10; ot += 4) {
    const float* wbase = (ot == 0) ? wq : (ot == 1) ? wk : wv + (ot - 2) * 16 * 128;
    const float* bias  = (ot == 0) ? bq : (ot == 1) ? bk : bv + (ot - 2) * 16;
    const float4* wr = reinterpret_cast<const float4*>(wbase + cq * 128);

    f32x4 acc[4] = {zero4, zero4, zero4, zero4};
#pragma unroll
    for (int ks = 0; ks < 4; ++ks) {
      float4 f0 = wr[ks * 8 + g * 2];
      float4 f1 = wr[ks * 8 + g * 2 + 1];
      bf16x8 af;
      af[0] = (__bf16)f0.x; af[1] = (__bf16)f0.y;
      af[2] = (__bf16)f0.z; af[3] = (__bf16)f0.w;
      af[4] = (__bf16)f1.x; af[5] = (__bf16)f1.y;
      af[6] = (__bf16)f1.z; af[7] = (__bf16)f1.w;
#pragma unroll
      for (int nf = 0; nf < 4; ++nf) {
        bf16x8 bfr = *reinterpret_cast<const bf16x8*>(
            &xs[(nf * 16 + cq) * 136 + ks * 32 + g8]);
        acc[nf] = __builtin_amdgcn_mfma_f32_16x16x32_bf16(af, bfr, acc[nf], 0, 0, 0);
      }
    }

    float4 bl = *reinterpret_cast<const float4*>(bias + g4);
    const float* blp = reinterpret_cast<const float*>(&bl);
#pragma unroll
    for (int nf = 0; nf < 4; ++nf) {
      int n = n0 + nf * 16 + cq;
#pragma unroll
      for (int v = 0; v < 4; ++v) {
        float val = acc[nf][v] + blp[v];
        int o = g4 + v;
        if (ot == 0) {
          qt[(size_t)(b * 4096 + n) * 32 + o] = (__bf16)val;
          qt[(size_t)(b * 4096 + n) * 32 + 16 + o] = (__bf16)0.f;
        } else if (ot == 1) {
          kt[(size_t)(b * 4096 + n) * 32 + o] = (__bf16)val;
          kt[(size_t)(b * 4096 + n) * 32 + 16 + o] = (__bf16)0.f;
        } else {
          vt[(size_t)(b * 128 + (ot - 2) * 16 + o) * N_VOX + n] = (__bf16)val;
        }
      }
    }
  }
}

// ---------------------------------------------------------------------------
// Kernel 2: fused flash attention (bf16 MFMA) + gamma*out + x
// grid = 512 : (b, 16-query tile). 8 waves/block (512 thr), 512 keys/wave.
// Bulk V-fragment register batching (8 at a time) to amortize L2 latency.
// ---------------------------------------------------------------------------
__global__ __launch_bounds__(512, 4) void attn_kernel(
    const __bf16* __restrict__ ws,
    const float* __restrict__ x,
    const float* __restrict__ gamma_p,
    float* __restrict__ out) {
  __shared__ __align__(16) ushort ps_raw[8][16 * 72];   // 18.4 KB
  __shared__ float o_lds[4][128][17];                   // 34.8 KB
  __shared__ float m_lds[8][16], l_lds[8][16], lstar_lds[16];

  const int t    = threadIdx.x;
  const int w    = t >> 6;          // wave 0..7
  const int lane = t & 63;
  const int cq   = lane & 15;
  const int g    = lane >> 4;
  const int g8   = g * 8;
  const int g4   = g * 4;

  const int bid = blockIdx.x;       // 512
  const int b   = bid >> 8;
  const int qt0 = (bid & 255) * 16;

  const __bf16* qt = ws;
  const __bf16* kt = ws + 262144;
  const __bf16* vt = ws + 524288;

  bf16x8 qfrag = *reinterpret_cast<const bf16x8*>(
      qt + (size_t)(b * 4096 + qt0 + cq) * 32 + g8);

  f32x4 acc[8];
  const f32x4 zero4 = {0.f, 0.f, 0.f, 0.f};
#pragma unroll
  for (int ct = 0; ct < 8; ++ct) acc[ct] = zero4;
  float m = -1e30f, l = 0.f;

  __bf16* psw = reinterpret_cast<__bf16*>(&ps_raw[w][0]) + cq * 72;
  const __bf16* vrow = vt + (size_t)(b * 128 + cq) * 4096;

  const int j_base = w * 512;
#pragma unroll 1
  for (int tile = 0; tile < 8; ++tile) {
    const int j0 = j_base + tile * 64;

    // ---- QK^T ----
    f32x4 sf[4];
#pragma unroll
    for (int s = 0; s < 4; ++s) {
      bf16x8 kf = *reinterpret_cast<const bf16x8*>(
          kt + (size_t)(b * 4096 + j0 + s * 16 + cq) * 32 + g8);
      sf[s] = __builtin_amdgcn_mfma_f32_16x16x32_bf16(kf, qfrag, zero4, 0, 0, 0);
    }

    // ---- online softmax ----
    float tmax = sf[0][0];
#pragma unroll
    for (int s = 0; s < 4; ++s)
#pragma unroll
      for (int v = 0; v < 4; ++v) tmax = fmaxf(tmax, sf[s][v]);
    tmax = fmaxf(tmax, __shfl_xor(tmax, 16));
    tmax = fmaxf(tmax, __shfl_xor(tmax, 32));

    if (!__all(tmax <= m + 8.0f)) {           // defer-max (T13)
      float m_new = fmaxf(m, tmax);
      float sc = __expf(m - m_new);
#pragma unroll
      for (int ct = 0; ct < 8; ++ct) acc[ct] *= sc;
      l *= sc;
      m = m_new;
    }

    float psum = 0.f;
#pragma unroll
    for (int s = 0; s < 4; ++s) {
      bf16x4 pk;
#pragma unroll
      for (int v = 0; v < 4; ++v) {
        float p = __expf(sf[s][v] - m);
        psum += p;
        pk[v] = (__bf16)p;
      }
      *reinterpret_cast<bf16x4*>(psw + s * 16 + g4) = pk;
    }
    psum += __shfl_xor(psum, 16);
    psum += __shfl_xor(psum, 32);
    l += psum;

    // ---- PV with bulk register batching (8 fragments in flight) ----
#pragma unroll
    for (int cn = 0; cn < 2; ++cn) {
      bf16x8 vf[8];
#pragma unroll
      for (int ct = 0; ct < 8; ++ct)
        vf[ct] = *reinterpret_cast<const bf16x8*>(
            vrow + (size_t)ct * 16 * 4096 + j0 + cn * 32 + g8);
      bf16x8 pfrag = *reinterpret_cast<const bf16x8*>(psw + cn * 32 + g8);
#pragma unroll
      for (int ct = 0; ct < 8; ++ct)
        acc[ct] = __builtin_amdgcn_mfma_f32_16x16x32_bf16(vf[ct], pfrag, acc[ct], 0, 0, 0);
    }
  }

  // ---- cross-wave merge: 8 partials, 2-level tree into 4 LDS regions ----
  if (lane < 16) { m_lds[w][lane] = m; l_lds[w][lane] = l; }
  __syncthreads();

  float mstar = m_lds[0][cq];
#pragma unroll
  for (int ww = 1; ww < 8; ++ww) mstar = fmaxf(mstar, m_lds[ww][cq]);
  float lstar = 0.f;
#pragma unroll
  for (int ww = 0; ww < 8; ++ww)
    lstar += l_lds[ww][cq] * __expf(m_lds[ww][cq] - mstar);
  float myscale = __expf(m - mstar);
  if (w == 0 && lane < 16) lstar_lds[lane] = lstar;

  const int r = w & 3;
  if (w < 4) {
#pragma unroll
    for (int ct = 0; ct < 8; ++ct)
#pragma unroll
      for (int v = 0; v < 4; ++v)
        o_lds[r][ct * 16 + g4 + v][cq] = acc[ct][v] * myscale;
  }
  __syncthreads();
  if (w >= 4) {
#pragma unroll
    for (int ct = 0; ct < 8; ++ct)
#pragma unroll
      for (int v = 0; v < 4; ++v)
        o_lds[r][ct * 16 + g4 + v][cq] += acc[ct][v] * myscale;
  }
  __syncthreads();

  // ---- epilogue: out = gamma * O/l + x ----
  const float g0 = gamma_p[0];
  for (int idx = t; idx < 128 * 16; idx += 512) {
    int c = idx >> 4, qq = idx & 15;
    float o = (o_lds[0][c][qq] + o_lds[1][c][qq] +
               o_lds[2][c][qq] + o_lds[3][c][qq]) / lstar_lds[qq];
    size_t addr = (size_t)(b * 128 + c) * N_VOX + qt0 + qq;
    out[addr] = fmaf(g0, o, x[addr]);
  }
}

// ---------------------------------------------------------------------------
extern "C" void kernel_launch(void* const* d_in, const int* in_sizes, int n_in,
                              void* d_out, int out_size, void* d_ws, size_t ws_size,
                              hipStream_t stream) {
  const float* x     = (const float*)d_in[0];
  const float* wq    = (const float*)d_in[1];
  const float* bq    = (const float*)d_in[2];
  const float* wk    = (const float*)d_in[3];
  const float* bk    = (const float*)d_in[4];
  const float* wv    = (const float*)d_in[5];
  const float* bv    = (const float*)d_in[6];
  const float* gamma = (const float*)d_in[7];
  float* out = (float*)d_out;
  __bf16* ws = (__bf16*)d_ws;   // 3 MB

  proj_kernel<<<128, 256, 0, stream>>>(x, wq, bq, wk, bk, wv, bv, ws);
  attn_kernel<<<512, 512, 0, stream>>>(ws, x, gamma, out);
}

// Round 4
// 54.183 us; speedup vs baseline: 7.7070x; 1.5885x over previous
//
#include <hip/hip_runtime.h>
#include <hip/hip_bf16.h>
#include <math.h>

#define N_VOX 4096

typedef __bf16 bf16x8 __attribute__((ext_vector_type(8)));
typedef __bf16 bf16x4 __attribute__((ext_vector_type(4)));
typedef float f32x4 __attribute__((ext_vector_type(4)));

// ws layout (bf16 elements):
//   qt[b][n][32]  @ 0        (rows zero-padded 16..31)   262144
//   kt[b][n][32]  @ 262144                               262144
//   v [b][c][n]   @ 524288                               1048576

__device__ __forceinline__ f32x4 mfma16(f32x4 a, f32x4 b, f32x4 c) {
  return __builtin_amdgcn_mfma_f32_16x16x32_bf16(
      __builtin_bit_cast(bf16x8, a), __builtin_bit_cast(bf16x8, b), c, 0, 0, 0);
}
__device__ __forceinline__ void pin(f32x4& v) { asm volatile("" : "+v"(v)); }

// ---------------------------------------------------------------------------
// Kernel 1: q/k/v projections as MFMA GEMM. grid = 2 x 128 n-tiles of 32.
// ---------------------------------------------------------------------------
__global__ __launch_bounds__(256) void proj_kernel(
    const float* __restrict__ x,
    const float* __restrict__ wq, const float* __restrict__ bq,
    const float* __restrict__ wk, const float* __restrict__ bk,
    const float* __restrict__ wv, const float* __restrict__ bv,
    __bf16* __restrict__ ws) {
  __shared__ __bf16 xs[32 * 136];   // [n][c], row stride 136

  const int t   = threadIdx.x;
  const int bid = blockIdx.x;       // 256 = 2 * 128
  const int b   = bid >> 7;
  const int n0  = (bid & 127) * 32;

  // stage x tile transposed, vectorized float4 reads
  for (int idx = t; idx < 128 * 8; idx += 256) {
    int c = idx >> 3, v4 = idx & 7;
    float4 xv = *reinterpret_cast<const float4*>(
        x + (size_t)(b * 128 + c) * N_VOX + n0 + v4 * 4);
    xs[(v4 * 4 + 0) * 136 + c] = (__bf16)xv.x;
    xs[(v4 * 4 + 1) * 136 + c] = (__bf16)xv.y;
    xs[(v4 * 4 + 2) * 136 + c] = (__bf16)xv.z;
    xs[(v4 * 4 + 3) * 136 + c] = (__bf16)xv.w;
  }
  __syncthreads();

  const int w = t >> 6, lane = t & 63;
  const int cq = lane & 15, g = lane >> 4, g8 = g * 8, g4 = g * 4;

  __bf16* qt = ws;
  __bf16* kt = ws + 262144;
  __bf16* vt = ws + 524288;
  const f32x4 zero4 = {0.f, 0.f, 0.f, 0.f};

  for (int ot = w; ot < 10; ot += 4) {
    const float* wbase = (ot == 0) ? wq : (ot == 1) ? wk : wv + (ot - 2) * 16 * 128;
    const float* bias  = (ot == 0) ? bq : (ot == 1) ? bk : bv + (ot - 2) * 16;
    const float4* wr = reinterpret_cast<const float4*>(wbase + cq * 128);

    f32x4 acc[2] = {zero4, zero4};
#pragma unroll
    for (int ks = 0; ks < 4; ++ks) {
      float4 f0 = wr[ks * 8 + g * 2];
      float4 f1 = wr[ks * 8 + g * 2 + 1];
      bf16x8 af;
      af[0] = (__bf16)f0.x; af[1] = (__bf16)f0.y;
      af[2] = (__bf16)f0.z; af[3] = (__bf16)f0.w;
      af[4] = (__bf16)f1.x; af[5] = (__bf16)f1.y;
      af[6] = (__bf16)f1.z; af[7] = (__bf16)f1.w;
#pragma unroll
      for (int nf = 0; nf < 2; ++nf) {
        bf16x8 bfr = *reinterpret_cast<const bf16x8*>(
            &xs[(nf * 16 + cq) * 136 + ks * 32 + g8]);
        acc[nf] = __builtin_amdgcn_mfma_f32_16x16x32_bf16(af, bfr, acc[nf], 0, 0, 0);
      }
    }

    float4 bl = *reinterpret_cast<const float4*>(bias + g4);
    const float* blp = reinterpret_cast<const float*>(&bl);
#pragma unroll
    for (int nf = 0; nf < 2; ++nf) {
      int n = n0 + nf * 16 + cq;
#pragma unroll
      for (int v = 0; v < 4; ++v) {
        float val = acc[nf][v] + blp[v];
        int o = g4 + v;
        if (ot == 0) {
          qt[(size_t)(b * 4096 + n) * 32 + o] = (__bf16)val;
          qt[(size_t)(b * 4096 + n) * 32 + 16 + o] = (__bf16)0.f;
        } else if (ot == 1) {
          kt[(size_t)(b * 4096 + n) * 32 + o] = (__bf16)val;
          kt[(size_t)(b * 4096 + n) * 32 + 16 + o] = (__bf16)0.f;
        } else {
          vt[(size_t)(b * 128 + (ot - 2) * 16 + o) * N_VOX + n] = (__bf16)val;
        }
      }
    }
  }
}

// ---------------------------------------------------------------------------
// Kernel 2: fused flash attention. grid = 256 (b x 128 q-tiles of 32),
// 256 threads = 4 waves, each wave: 32 queries x 1024 keys (16 tiles of 64).
// V/K loads issued at tile top, pinned after softmax -> one batched wait/tile.
// ---------------------------------------------------------------------------
__global__ __launch_bounds__(256, 1) void attn_kernel(
    const __bf16* __restrict__ ws,
    const float* __restrict__ x,
    const float* __restrict__ gamma_p,
    float* __restrict__ out) {
  __shared__ __align__(16) __bf16 ps[4][32 * 72];   // per-wave P^T[q][j], 18.4 KB
  __shared__ float o_lds[2][128][33];               // 33.8 KB
  __shared__ float m_lds[4][32], l_lds[4][32], lstar_lds[32];

  const int t    = threadIdx.x;
  const int w    = t >> 6;
  const int lane = t & 63;
  const int cq   = lane & 15;
  const int g    = lane >> 4;
  const int g8   = g * 8;
  const int g4   = g * 4;

  // XCD-bijective swizzle: XCDs 0-3 -> batch 0, XCDs 4-7 -> batch 1
  const int raw = blockIdx.x;            // 256
  const int xcd = raw & 7;
  const int b   = xcd >> 2;
  const int qt0 = ((raw >> 3) * 4 + (xcd & 3)) * 32;

  const __bf16* qt = ws;
  const __bf16* kt = ws + 262144;
  const __bf16* vt = ws + 524288;

  f32x4 qfrag[2];
#pragma unroll
  for (int qf = 0; qf < 2; ++qf)
    qfrag[qf] = *reinterpret_cast<const f32x4*>(
        qt + (size_t)(b * 4096 + qt0 + qf * 16 + cq) * 32 + g8);

  const f32x4 zero4 = {0.f, 0.f, 0.f, 0.f};
  f32x4 acc[8][2];
#pragma unroll
  for (int ct = 0; ct < 8; ++ct) { acc[ct][0] = zero4; acc[ct][1] = zero4; }
  float m0 = -1e30f, m1 = -1e30f, l0 = 0.f, l1 = 0.f;

  __bf16* psw0 = &ps[w][cq * 72];
  __bf16* psw1 = &ps[w][(16 + cq) * 72];
  const __bf16* vrow  = vt + (size_t)(b * 128 + cq) * 4096;
  const __bf16* kbase = kt + (size_t)(b * 4096 + cq) * 32 + g8;

  const int j_base = w * 1024;

  f32x4 kf[4];
#pragma unroll
  for (int s = 0; s < 4; ++s)
    kf[s] = *reinterpret_cast<const f32x4*>(kbase + (size_t)(j_base + s * 16) * 32);

#pragma unroll 1
  for (int tile = 0; tile < 16; ++tile) {
    const int j0 = j_base + tile * 64;
    const int jn = j_base + ((tile + 1) & 15) * 64;

    // ---- issue all 16 V loads + 4 next-K loads (wait deferred to PV) ----
    f32x4 vf[2][8];
#pragma unroll
    for (int cn = 0; cn < 2; ++cn)
#pragma unroll
      for (int ct = 0; ct < 8; ++ct)
        vf[cn][ct] = *reinterpret_cast<const f32x4*>(
            vrow + (size_t)ct * 16 * 4096 + j0 + cn * 32 + g8);
    f32x4 kn[4];
#pragma unroll
    for (int s = 0; s < 4; ++s)
      kn[s] = *reinterpret_cast<const f32x4*>(kbase + (size_t)(jn + s * 16) * 32);

    // ---- QK^T: sf[s][qf], lane holds S^T[j=16s+g4+v][q=qf*16+cq] ----
    f32x4 sf[4][2];
#pragma unroll
    for (int s = 0; s < 4; ++s) {
      sf[s][0] = mfma16(kf[s], qfrag[0], zero4);
      sf[s][1] = mfma16(kf[s], qfrag[1], zero4);
    }

    // ---- online softmax (per qf) ----
    float tmax0 = sf[0][0][0], tmax1 = sf[0][1][0];
#pragma unroll
    for (int s = 0; s < 4; ++s)
#pragma unroll
      for (int v = 0; v < 4; ++v) {
        tmax0 = fmaxf(tmax0, sf[s][0][v]);
        tmax1 = fmaxf(tmax1, sf[s][1][v]);
      }
    tmax0 = fmaxf(tmax0, __shfl_xor(tmax0, 16));
    tmax0 = fmaxf(tmax0, __shfl_xor(tmax0, 32));
    tmax1 = fmaxf(tmax1, __shfl_xor(tmax1, 16));
    tmax1 = fmaxf(tmax1, __shfl_xor(tmax1, 32));

    if (__any((tmax0 > m0 + 8.0f) || (tmax1 > m1 + 8.0f))) {   // defer-max
      float m0n = fmaxf(m0, tmax0), m1n = fmaxf(m1, tmax1);
      float sc0 = __expf(m0 - m0n), sc1 = __expf(m1 - m1n);
#pragma unroll
      for (int ct = 0; ct < 8; ++ct) { acc[ct][0] *= sc0; acc[ct][1] *= sc1; }
      l0 *= sc0; l1 *= sc1;
      m0 = m0n; m1 = m1n;
    }

    float psum0 = 0.f, psum1 = 0.f;
#pragma unroll
    for (int s = 0; s < 4; ++s) {
      bf16x4 pk0, pk1;
#pragma unroll
      for (int v = 0; v < 4; ++v) {
        float p0 = __expf(sf[s][0][v] - m0);
        float p1 = __expf(sf[s][1][v] - m1);
        psum0 += p0; psum1 += p1;
        pk0[v] = (__bf16)p0; pk1[v] = (__bf16)p1;
      }
      *reinterpret_cast<bf16x4*>(psw0 + s * 16 + g4) = pk0;
      *reinterpret_cast<bf16x4*>(psw1 + s * 16 + g4) = pk1;
    }
    psum0 += __shfl_xor(psum0, 16); psum0 += __shfl_xor(psum0, 32);
    psum1 += __shfl_xor(psum1, 16); psum1 += __shfl_xor(psum1, 32);
    l0 += psum0; l1 += psum1;

    // ---- PV: pin V (single batched wait), then 32 MFMAs ----
#pragma unroll
    for (int cn = 0; cn < 2; ++cn)
#pragma unroll
      for (int ct = 0; ct < 8; ++ct) pin(vf[cn][ct]);
#pragma unroll
    for (int s = 0; s < 4; ++s) pin(kn[s]);

#pragma unroll
    for (int cn = 0; cn < 2; ++cn) {
      f32x4 pf0 = *reinterpret_cast<const f32x4*>(psw0 + cn * 32 + g8);
      f32x4 pf1 = *reinterpret_cast<const f32x4*>(psw1 + cn * 32 + g8);
#pragma unroll
      for (int ct = 0; ct < 8; ++ct) {
        acc[ct][0] = mfma16(vf[cn][ct], pf0, acc[ct][0]);
        acc[ct][1] = mfma16(vf[cn][ct], pf1, acc[ct][1]);
      }
    }

#pragma unroll
    for (int s = 0; s < 4; ++s) kf[s] = kn[s];
  }

  // ---- cross-wave merge (4 partials) ----
  if (lane < 16) {
    m_lds[w][cq] = m0; m_lds[w][16 + cq] = m1;
    l_lds[w][cq] = l0; l_lds[w][16 + cq] = l1;
  }
  __syncthreads();

  float mstar0 = m_lds[0][cq],      mstar1 = m_lds[0][16 + cq];
#pragma unroll
  for (int ww = 1; ww < 4; ++ww) {
    mstar0 = fmaxf(mstar0, m_lds[ww][cq]);
    mstar1 = fmaxf(mstar1, m_lds[ww][16 + cq]);
  }
  float lstar0 = 0.f, lstar1 = 0.f;
#pragma unroll
  for (int ww = 0; ww < 4; ++ww) {
    lstar0 += l_lds[ww][cq]      * __expf(m_lds[ww][cq]      - mstar0);
    lstar1 += l_lds[ww][16 + cq] * __expf(m_lds[ww][16 + cq] - mstar1);
  }
  float sc0 = __expf(m0 - mstar0), sc1 = __expf(m1 - mstar1);
  if (w == 0 && lane < 16) { lstar_lds[cq] = lstar0; lstar_lds[16 + cq] = lstar1; }

  if (w < 2) {
#pragma unroll
    for (int ct = 0; ct < 8; ++ct)
#pragma unroll
      for (int v = 0; v < 4; ++v) {
        o_lds[w][ct * 16 + g4 + v][cq]      = acc[ct][0][v] * sc0;
        o_lds[w][ct * 16 + g4 + v][16 + cq] = acc[ct][1][v] * sc1;
      }
  }
  __syncthreads();
  if (w >= 2) {
#pragma unroll
    for (int ct = 0; ct < 8; ++ct)
#pragma unroll
      for (int v = 0; v < 4; ++v) {
        o_lds[w - 2][ct * 16 + g4 + v][cq]      += acc[ct][0][v] * sc0;
        o_lds[w - 2][ct * 16 + g4 + v][16 + cq] += acc[ct][1][v] * sc1;
      }
  }
  __syncthreads();

  // ---- epilogue: out = gamma * O/l + x ----
  const float g0 = gamma_p[0];
  for (int idx = t; idx < 128 * 32; idx += 256) {
    int c = idx >> 5, qq = idx & 31;
    float o = (o_lds[0][c][qq] + o_lds[1][c][qq]) / lstar_lds[qq];
    size_t addr = (size_t)(b * 128 + c) * N_VOX + qt0 + qq;
    out[addr] = fmaf(g0, o, x[addr]);
  }
}

// ---------------------------------------------------------------------------
extern "C" void kernel_launch(void* const* d_in, const int* in_sizes, int n_in,
                              void* d_out, int out_size, void* d_ws, size_t ws_size,
                              hipStream_t stream) {
  const float* x     = (const float*)d_in[0];
  const float* wq    = (const float*)d_in[1];
  const float* bq    = (const float*)d_in[2];
  const float* wk    = (const float*)d_in[3];
  const float* bk    = (const float*)d_in[4];
  const float* wv    = (const float*)d_in[5];
  const float* bv    = (const float*)d_in[6];
  const float* gamma = (const float*)d_in[7];
  float* out = (float*)d_out;
  __bf16* ws = (__bf16*)d_ws;   // 3 MB

  proj_kernel<<<256, 256, 0, stream>>>(x, wq, bq, wk, bk, wv, bv, ws);
  attn_kernel<<<256, 256, 0, stream>>>(ws, x, gamma, out);
}

// Round 5
// 37.800 us; speedup vs baseline: 11.0472x; 1.4334x over previous
//
#include <hip/hip_runtime.h>
#include <hip/hip_bf16.h>
#include <math.h>

#define N_VOX 4096

typedef __bf16 bf16x8 __attribute__((ext_vector_type(8)));
typedef __bf16 bf16x4 __attribute__((ext_vector_type(4)));
typedef float f32x4 __attribute__((ext_vector_type(4)));

// ws layout (bf16 elements):
//   qt[b][n][32] @ 0        (rows zero-padded 16..31)            262144
//   kt[b][n][32] @ 262144                                        262144
//   vp packed    @ 524288:  (((b*64+jt)*8+ct)*2+cn)*512+lane*8+e 1048576
//   wqb[16][128] @ 1572864                                       2048
//   wkb[16][128] @ 1574912                                       2048
//   wvb[128][128]@ 1576960                                       16384
#define QT_OFF  0
#define KT_OFF  262144
#define VP_OFF  524288
#define WQ_OFF  1572864
#define WK_OFF  1574912
#define WV_OFF  1576960

__device__ __forceinline__ f32x4 mfma16(f32x4 a, f32x4 b, f32x4 c) {
  return __builtin_amdgcn_mfma_f32_16x16x32_bf16(
      __builtin_bit_cast(bf16x8, a), __builtin_bit_cast(bf16x8, b), c, 0, 0, 0);
}
__device__ __forceinline__ void pin(f32x4& v) { asm volatile("" : "+v"(v)); }

// ---------------------------------------------------------------------------
// Kernel 0: convert w matrices to bf16 once. 20480 elems, grid 20 x 256.
// ---------------------------------------------------------------------------
__global__ __launch_bounds__(256) void wcvt_kernel(
    const float* __restrict__ wq, const float* __restrict__ wk,
    const float* __restrict__ wv, __bf16* __restrict__ ws) {
  int gid = (blockIdx.x * 256 + threadIdx.x) * 4;   // 0..20476
  const float* src;
  __bf16* dst;
  if (gid < 2048)      { src = wq + gid;        dst = ws + WQ_OFF + gid; }
  else if (gid < 4096) { src = wk + gid - 2048; dst = ws + WK_OFF + gid - 2048; }
  else                 { src = wv + gid - 4096; dst = ws + WV_OFF + gid - 4096; }
  float4 f = *reinterpret_cast<const float4*>(src);
  bf16x4 o;
  o[0] = (__bf16)f.x; o[1] = (__bf16)f.y; o[2] = (__bf16)f.z; o[3] = (__bf16)f.w;
  *reinterpret_cast<bf16x4*>(dst) = o;
}

// ---------------------------------------------------------------------------
// Kernel 1: q/k/v projections as MFMA GEMM. grid = 2 x 128 n-tiles of 32.
// V written in packed wave-linear fragment order.
// ---------------------------------------------------------------------------
__global__ __launch_bounds__(256) void proj_kernel(
    const float* __restrict__ x,
    const float* __restrict__ bq, const float* __restrict__ bk,
    const float* __restrict__ bv,
    __bf16* __restrict__ ws) {
  __shared__ __bf16 xs[32 * 136];   // [n][c], row stride 136

  const int t   = threadIdx.x;
  const int bid = blockIdx.x;       // 256 = 2 * 128
  const int b   = bid >> 7;
  const int n0  = (bid & 127) * 32;

  for (int idx = t; idx < 128 * 8; idx += 256) {
    int c = idx >> 3, v4 = idx & 7;
    float4 xv = *reinterpret_cast<const float4*>(
        x + (size_t)(b * 128 + c) * N_VOX + n0 + v4 * 4);
    xs[(v4 * 4 + 0) * 136 + c] = (__bf16)xv.x;
    xs[(v4 * 4 + 1) * 136 + c] = (__bf16)xv.y;
    xs[(v4 * 4 + 2) * 136 + c] = (__bf16)xv.z;
    xs[(v4 * 4 + 3) * 136 + c] = (__bf16)xv.w;
  }
  __syncthreads();

  const int w = t >> 6, lane = t & 63;
  const int cq = lane & 15, g = lane >> 4, g8 = g * 8, g4 = g * 4;

  __bf16* qt = ws + QT_OFF;
  __bf16* kt = ws + KT_OFF;
  __bf16* vp = ws + VP_OFF;
  const f32x4 zero4 = {0.f, 0.f, 0.f, 0.f};

  for (int ot = w; ot < 10; ot += 4) {
    const __bf16* wb = (ot == 0) ? ws + WQ_OFF + cq * 128
                     : (ot == 1) ? ws + WK_OFF + cq * 128
                                 : ws + WV_OFF + ((ot - 2) * 16 + cq) * 128;
    const float* bias = (ot == 0) ? bq : (ot == 1) ? bk : bv + (ot - 2) * 16;

    f32x4 acc[2] = {zero4, zero4};
#pragma unroll
    for (int ks = 0; ks < 4; ++ks) {
      bf16x8 af = *reinterpret_cast<const bf16x8*>(wb + ks * 32 + g8);
#pragma unroll
      for (int nf = 0; nf < 2; ++nf) {
        bf16x8 bfr = *reinterpret_cast<const bf16x8*>(
            &xs[(nf * 16 + cq) * 136 + ks * 32 + g8]);
        acc[nf] = __builtin_amdgcn_mfma_f32_16x16x32_bf16(af, bfr, acc[nf], 0, 0, 0);
      }
    }

    float4 bl = *reinterpret_cast<const float4*>(bias + g4);
    const float* blp = reinterpret_cast<const float*>(&bl);
#pragma unroll
    for (int nf = 0; nf < 2; ++nf) {
      int n = n0 + nf * 16 + cq;
#pragma unroll
      for (int v = 0; v < 4; ++v) {
        float val = acc[nf][v] + blp[v];
        int o = g4 + v;
        if (ot == 0) {
          qt[(size_t)(b * 4096 + n) * 32 + o] = (__bf16)val;
          qt[(size_t)(b * 4096 + n) * 32 + 16 + o] = (__bf16)0.f;
        } else if (ot == 1) {
          kt[(size_t)(b * 4096 + n) * 32 + o] = (__bf16)val;
          kt[(size_t)(b * 4096 + n) * 32 + 16 + o] = (__bf16)0.f;
        } else {
          int c  = (ot - 2) * 16 + o;
          int jt = n >> 6, j_in = n & 63;
          int cn = j_in >> 5, gg = (j_in & 31) >> 3, e = j_in & 7;
          int lt = (c & 15) | (gg << 4);
          vp[((((size_t)b * 64 + jt) * 8 + (c >> 4)) * 2 + cn) * 512 + lt * 8 + e]
              = (__bf16)val;
        }
      }
    }
  }
}

// ---------------------------------------------------------------------------
// Kernel 2: fused flash attention. grid = 256 (b x 128 q-tiles of 32),
// 512 threads = 8 waves, each wave: 32 queries x 512 keys (8 tiles of 64).
// Packed-V coalesced loads; issue-early / pin-late (one batched wait/tile).
// ---------------------------------------------------------------------------
__global__ __launch_bounds__(512, 2) void attn_kernel(
    const __bf16* __restrict__ ws,
    const float* __restrict__ x,
    const float* __restrict__ gamma_p,
    float* __restrict__ out) {
  __shared__ __align__(16) __bf16 ps[8][32 * 72];   // per-wave P^T[q][j], 36.9 KB
  __shared__ float o_lds[4][128][33];               // 67.6 KB
  __shared__ float m_lds[8][32], l_lds[8][32], lstar_lds[32];

  const int t    = threadIdx.x;
  const int w    = t >> 6;
  const int lane = t & 63;
  const int cq   = lane & 15;
  const int g    = lane >> 4;
  const int g8   = g * 8;
  const int g4   = g * 4;

  // XCD-bijective swizzle: XCDs 0-3 -> batch 0, XCDs 4-7 -> batch 1
  const int raw = blockIdx.x;            // 256
  const int xcd = raw & 7;
  const int b   = xcd >> 2;
  const int qt0 = ((raw >> 3) * 4 + (xcd & 3)) * 32;

  const __bf16* qt = ws + QT_OFF;
  const __bf16* kt = ws + KT_OFF;
  const __bf16* vp = ws + VP_OFF;

  f32x4 qfrag[2];
#pragma unroll
  for (int qf = 0; qf < 2; ++qf)
    qfrag[qf] = *reinterpret_cast<const f32x4*>(
        qt + (size_t)(b * 4096 + qt0 + qf * 16 + cq) * 32 + g8);

  const f32x4 zero4 = {0.f, 0.f, 0.f, 0.f};
  f32x4 acc[8][2];
#pragma unroll
  for (int ct = 0; ct < 8; ++ct) { acc[ct][0] = zero4; acc[ct][1] = zero4; }
  float m0 = -1e30f, m1 = -1e30f, l0 = 0.f, l1 = 0.f;

  __bf16* psw0 = &ps[w][cq * 72];
  __bf16* psw1 = &ps[w][(16 + cq) * 72];
  const __bf16* kbase = kt + (size_t)(b * 4096 + cq) * 32 + g8;
  // packed V base for this lane: + (((b*64+jt)*8+ct)*2+cn)*512 + lane*8
  const __bf16* vbase = vp + (size_t)b * 64 * 8192 + lane * 8;

  const int jt_base = w * 8;             // wave covers j-tiles [w*8, w*8+8)

  f32x4 kf[4];
#pragma unroll
  for (int s = 0; s < 4; ++s)
    kf[s] = *reinterpret_cast<const f32x4*>(
        kbase + (size_t)(jt_base * 64 + s * 16) * 32);

#pragma unroll 1
  for (int tile = 0; tile < 8; ++tile) {
    const int jt = jt_base + tile;
    const int jn = jt_base + ((tile + 1) & 7);

    // ---- issue all 16 packed-V loads + 4 next-K loads ----
    f32x4 vf[2][8];
#pragma unroll
    for (int cn = 0; cn < 2; ++cn)
#pragma unroll
      for (int ct = 0; ct < 8; ++ct)
        vf[cn][ct] = *reinterpret_cast<const f32x4*>(
            vbase + (((size_t)jt * 8 + ct) * 2 + cn) * 512);
    f32x4 kn[4];
#pragma unroll
    for (int s = 0; s < 4; ++s)
      kn[s] = *reinterpret_cast<const f32x4*>(
          kbase + (size_t)(jn * 64 + s * 16) * 32);

    // ---- QK^T: lane holds S^T[j=jt*64+16s+g4+v][q=qf*16+cq] ----
    f32x4 sf[4][2];
#pragma unroll
    for (int s = 0; s < 4; ++s) {
      sf[s][0] = mfma16(kf[s], qfrag[0], zero4);
      sf[s][1] = mfma16(kf[s], qfrag[1], zero4);
    }

    // ---- online softmax ----
    float tmax0 = sf[0][0][0], tmax1 = sf[0][1][0];
#pragma unroll
    for (int s = 0; s < 4; ++s)
#pragma unroll
      for (int v = 0; v < 4; ++v) {
        tmax0 = fmaxf(tmax0, sf[s][0][v]);
        tmax1 = fmaxf(tmax1, sf[s][1][v]);
      }
    tmax0 = fmaxf(tmax0, __shfl_xor(tmax0, 16));
    tmax0 = fmaxf(tmax0, __shfl_xor(tmax0, 32));
    tmax1 = fmaxf(tmax1, __shfl_xor(tmax1, 16));
    tmax1 = fmaxf(tmax1, __shfl_xor(tmax1, 32));

    if (__any((tmax0 > m0 + 8.0f) || (tmax1 > m1 + 8.0f))) {   // defer-max
      float m0n = fmaxf(m0, tmax0), m1n = fmaxf(m1, tmax1);
      float sc0 = __expf(m0 - m0n), sc1 = __expf(m1 - m1n);
#pragma unroll
      for (int ct = 0; ct < 8; ++ct) { acc[ct][0] *= sc0; acc[ct][1] *= sc1; }
      l0 *= sc0; l1 *= sc1;
      m0 = m0n; m1 = m1n;
    }

    float psum0 = 0.f, psum1 = 0.f;
#pragma unroll
    for (int s = 0; s < 4; ++s) {
      bf16x4 pk0, pk1;
#pragma unroll
      for (int v = 0; v < 4; ++v) {
        float p0 = __expf(sf[s][0][v] - m0);
        float p1 = __expf(sf[s][1][v] - m1);
        psum0 += p0; psum1 += p1;
        pk0[v] = (__bf16)p0; pk1[v] = (__bf16)p1;
      }
      *reinterpret_cast<bf16x4*>(psw0 + s * 16 + g4) = pk0;
      *reinterpret_cast<bf16x4*>(psw1 + s * 16 + g4) = pk1;
    }
    psum0 += __shfl_xor(psum0, 16); psum0 += __shfl_xor(psum0, 32);
    psum1 += __shfl_xor(psum1, 16); psum1 += __shfl_xor(psum1, 32);
    l0 += psum0; l1 += psum1;

    // ---- PV: pin loads (single batched wait), then 32 MFMAs ----
#pragma unroll
    for (int cn = 0; cn < 2; ++cn)
#pragma unroll
      for (int ct = 0; ct < 8; ++ct) pin(vf[cn][ct]);
#pragma unroll
    for (int s = 0; s < 4; ++s) pin(kn[s]);

#pragma unroll
    for (int cn = 0; cn < 2; ++cn) {
      f32x4 pf0 = *reinterpret_cast<const f32x4*>(psw0 + cn * 32 + g8);
      f32x4 pf1 = *reinterpret_cast<const f32x4*>(psw1 + cn * 32 + g8);
#pragma unroll
      for (int ct = 0; ct < 8; ++ct) {
        acc[ct][0] = mfma16(vf[cn][ct], pf0, acc[ct][0]);
        acc[ct][1] = mfma16(vf[cn][ct], pf1, acc[ct][1]);
      }
    }

#pragma unroll
    for (int s = 0; s < 4; ++s) kf[s] = kn[s];
  }

  // ---- cross-wave merge (8 partials) ----
  if (lane < 16) {
    m_lds[w][cq] = m0; m_lds[w][16 + cq] = m1;
    l_lds[w][cq] = l0; l_lds[w][16 + cq] = l1;
  }
  __syncthreads();

  float mstar0 = m_lds[0][cq],      mstar1 = m_lds[0][16 + cq];
#pragma unroll
  for (int ww = 1; ww < 8; ++ww) {
    mstar0 = fmaxf(mstar0, m_lds[ww][cq]);
    mstar1 = fmaxf(mstar1, m_lds[ww][16 + cq]);
  }
  float lstar0 = 0.f, lstar1 = 0.f;
#pragma unroll
  for (int ww = 0; ww < 8; ++ww) {
    lstar0 += l_lds[ww][cq]      * __expf(m_lds[ww][cq]      - mstar0);
    lstar1 += l_lds[ww][16 + cq] * __expf(m_lds[ww][16 + cq] - mstar1);
  }
  float sc0 = __expf(m0 - mstar0), sc1 = __expf(m1 - mstar1);
  if (w == 0 && lane < 16) { lstar_lds[cq] = lstar0; lstar_lds[16 + cq] = lstar1; }

  const int r = w & 3;
  if (w < 4) {
#pragma unroll
    for (int ct = 0; ct < 8; ++ct)
#pragma unroll
      for (int v = 0; v < 4; ++v) {
        o_lds[r][ct * 16 + g4 + v][cq]      = acc[ct][0][v] * sc0;
        o_lds[r][ct * 16 + g4 + v][16 + cq] = acc[ct][1][v] * sc1;
      }
  }
  __syncthreads();
  if (w >= 4) {
#pragma unroll
    for (int ct = 0; ct < 8; ++ct)
#pragma unroll
      for (int v = 0; v < 4; ++v) {
        o_lds[r][ct * 16 + g4 + v][cq]      += acc[ct][0][v] * sc0;
        o_lds[r][ct * 16 + g4 + v][16 + cq] += acc[ct][1][v] * sc1;
      }
  }
  __syncthreads();

  // ---- epilogue: out = gamma * O/l + x ----
  const float g0 = gamma_p[0];
  for (int idx = t; idx < 128 * 32; idx += 512) {
    int c = idx >> 5, qq = idx & 31;
    float o = (o_lds[0][c][qq] + o_lds[1][c][qq] +
               o_lds[2][c][qq] + o_lds[3][c][qq]) / lstar_lds[qq];
    size_t addr = (size_t)(b * 128 + c) * N_VOX + qt0 + qq;
    out[addr] = fmaf(g0, o, x[addr]);
  }
}

// ---------------------------------------------------------------------------
extern "C" void kernel_launch(void* const* d_in, const int* in_sizes, int n_in,
                              void* d_out, int out_size, void* d_ws, size_t ws_size,
                              hipStream_t stream) {
  const float* x     = (const float*)d_in[0];
  const float* wq    = (const float*)d_in[1];
  const float* bq    = (const float*)d_in[2];
  const float* wk    = (const float*)d_in[3];
  const float* bk    = (const float*)d_in[4];
  const float* wv    = (const float*)d_in[5];
  const float* bv    = (const float*)d_in[6];
  const float* gamma = (const float*)d_in[7];
  float* out = (float*)d_out;
  __bf16* ws = (__bf16*)d_ws;   // ~3.1 MB

  wcvt_kernel<<<20, 256, 0, stream>>>(wq, wk, wv, ws);
  proj_kernel<<<256, 256, 0, stream>>>(x, bq, bk, bv, ws);
  attn_kernel<<<256, 512, 0, stream>>>(ws, x, gamma, out);
}

// Round 7
// 34.664 us; speedup vs baseline: 12.0468x; 1.0905x over previous
//
#include <hip/hip_runtime.h>
#include <hip/hip_bf16.h>
#include <math.h>

#define N_VOX 4096

typedef __bf16 bf16x8 __attribute__((ext_vector_type(8)));
typedef __bf16 bf16x4 __attribute__((ext_vector_type(4)));
typedef float f32x4 __attribute__((ext_vector_type(4)));

// ws layout (BYTES):
//   qt bf16[2][4096][32] @ 0        (cols 16..31 zero)   524288 B
//   kt bf16[2][4096][32] @ 524288                        524288 B
//   vp fp8  packed       @ 1048576                       1048576 B
//     byte index: (((b*64+jt)*8+ct)*2+cn)*512 + lane*8 + e
#define QT_OFF  0
#define KT_OFF  524288
#define VP_OFF  1048576

// P is stored as p' = exp(s - m - ln8) so max p' = e^(8-ln8) = 372 < 448
// (e4m3fn max). All waves share the shift, so O = acc'/l' is exact.
#define P_LN8 2.0794415f

__device__ __forceinline__ f32x4 mfma16(f32x4 a, f32x4 b, f32x4 c) {
  return __builtin_amdgcn_mfma_f32_16x16x32_bf16(
      __builtin_bit_cast(bf16x8, a), __builtin_bit_cast(bf16x8, b), c, 0, 0, 0);
}
__device__ __forceinline__ void pin(f32x4& v) { asm volatile("" : "+v"(v)); }
__device__ __forceinline__ void pinl(long& v) { asm volatile("" : "+v"(v)); }

__device__ __forceinline__ unsigned f32_to_fp8x4(float a, float b, float c, float d) {
  int v = __builtin_amdgcn_cvt_pk_fp8_f32(a, b, 0, false);
  v = __builtin_amdgcn_cvt_pk_fp8_f32(c, d, v, true);
  return (unsigned)v;
}
__device__ __forceinline__ unsigned char f32_to_fp8(float a) {
  return (unsigned char)(__builtin_amdgcn_cvt_pk_fp8_f32(a, a, 0, false) & 0xff);
}

// ---------------------------------------------------------------------------
// Kernel 1: q/k/v projections as MFMA GEMM (w converted to bf16 in LDS).
// grid = 2 x 128 n-tiles of 32, 256 threads.
// ---------------------------------------------------------------------------
__global__ __launch_bounds__(256) void proj_kernel(
    const float* __restrict__ x,
    const float* __restrict__ wq, const float* __restrict__ bq,
    const float* __restrict__ wk, const float* __restrict__ bk,
    const float* __restrict__ wv, const float* __restrict__ bv,
    unsigned char* __restrict__ ws8) {
  __shared__ __bf16 xs[32 * 136];    // [n][c] pad 136            8.7 KB
  __shared__ __bf16 wb[160 * 136];   // rows: q 0-15,k 16-31,v 32-159  43.5 KB

  const int t   = threadIdx.x;
  const int bid = blockIdx.x;        // 256 = 2 * 128
  const int b   = bid >> 7;
  const int n0  = (bid & 127) * 32;

  // stage w (fp32 -> bf16), 20480 elems
  for (int i = t; i < 5120; i += 256) {
    int gid = i * 4;
    const float* src = (gid < 2048) ? wq + gid
                     : (gid < 4096) ? wk + (gid - 2048)
                                    : wv + (gid - 4096);
    float4 f = *reinterpret_cast<const float4*>(src);
    int r = gid >> 7, col = gid & 127;
    bf16x4 o;
    o[0] = (__bf16)f.x; o[1] = (__bf16)f.y; o[2] = (__bf16)f.z; o[3] = (__bf16)f.w;
    *reinterpret_cast<bf16x4*>(&wb[r * 136 + col]) = o;
  }
  // stage x tile transposed
  for (int idx = t; idx < 128 * 8; idx += 256) {
    int c = idx >> 3, v4 = idx & 7;
    float4 xv = *reinterpret_cast<const float4*>(
        x + (size_t)(b * 128 + c) * N_VOX + n0 + v4 * 4);
    xs[(v4 * 4 + 0) * 136 + c] = (__bf16)xv.x;
    xs[(v4 * 4 + 1) * 136 + c] = (__bf16)xv.y;
    xs[(v4 * 4 + 2) * 136 + c] = (__bf16)xv.z;
    xs[(v4 * 4 + 3) * 136 + c] = (__bf16)xv.w;
  }
  __syncthreads();

  const int w = t >> 6, lane = t & 63;
  const int cq = lane & 15, g = lane >> 4, g8 = g * 8, g4 = g * 4;

  __bf16* qt = reinterpret_cast<__bf16*>(ws8 + QT_OFF);
  __bf16* kt = reinterpret_cast<__bf16*>(ws8 + KT_OFF);
  unsigned char* vp = ws8 + VP_OFF;
  const f32x4 zero4 = {0.f, 0.f, 0.f, 0.f};

  for (int ot = w; ot < 10; ot += 4) {
    int wrow = (ot == 0) ? cq : (ot == 1) ? 16 + cq : 32 + (ot - 2) * 16 + cq;
    const float* bias = (ot == 0) ? bq : (ot == 1) ? bk : bv + (ot - 2) * 16;

    f32x4 acc[2] = {zero4, zero4};
#pragma unroll
    for (int ks = 0; ks < 4; ++ks) {
      bf16x8 af = *reinterpret_cast<const bf16x8*>(&wb[wrow * 136 + ks * 32 + g8]);
#pragma unroll
      for (int nf = 0; nf < 2; ++nf) {
        bf16x8 bfr = *reinterpret_cast<const bf16x8*>(
            &xs[(nf * 16 + cq) * 136 + ks * 32 + g8]);
        acc[nf] = __builtin_amdgcn_mfma_f32_16x16x32_bf16(af, bfr, acc[nf], 0, 0, 0);
      }
    }

    float4 bl = *reinterpret_cast<const float4*>(bias + g4);
    const float* blp = reinterpret_cast<const float*>(&bl);
#pragma unroll
    for (int nf = 0; nf < 2; ++nf) {
      int n = n0 + nf * 16 + cq;
#pragma unroll
      for (int v = 0; v < 4; ++v) {
        float val = acc[nf][v] + blp[v];
        int o = g4 + v;
        if (ot == 0) {
          qt[(size_t)(b * 4096 + n) * 32 + o] = (__bf16)val;
          qt[(size_t)(b * 4096 + n) * 32 + 16 + o] = (__bf16)0.f;
        } else if (ot == 1) {
          kt[(size_t)(b * 4096 + n) * 32 + o] = (__bf16)val;
          kt[(size_t)(b * 4096 + n) * 32 + 16 + o] = (__bf16)0.f;
        } else {
          int c  = (ot - 2) * 16 + o;
          int jt = n >> 6, j_in = n & 63;
          int cn = j_in >> 5, gg = (j_in & 31) >> 3, e = j_in & 7;
          int lt = (c & 15) | (gg << 4);
          vp[((((size_t)b * 64 + jt) * 8 + (c >> 4)) * 2 + cn) * 512 + lt * 8 + e]
              = f32_to_fp8(val);
        }
      }
    }
  }
}

// ---------------------------------------------------------------------------
// Kernel 2: fused flash attention. grid = 256 (b x 128 q-tiles of 32),
// 512 threads = 8 waves, each wave: 32 queries x 512 keys (8 tiles of 64).
// QK^T bf16 MFMA; PV fp8 MFMA (V and shifted-P in e4m3). Issue-early/pin-late.
// ---------------------------------------------------------------------------
__global__ __launch_bounds__(512, 2) void attn_kernel(
    const unsigned char* __restrict__ ws8,
    const float* __restrict__ x,
    const float* __restrict__ gamma_p,
    float* __restrict__ out) {
  __shared__ __align__(16) unsigned char ps[8][32 * 72];  // P^T fp8, 18.4 KB
  __shared__ float o_lds[4][128][33];                     // 67.6 KB
  __shared__ float m_lds[8][32], l_lds[8][32], lstar_lds[32];

  const int t    = threadIdx.x;
  const int w    = t >> 6;
  const int lane = t & 63;
  const int cq   = lane & 15;
  const int g    = lane >> 4;
  const int g8   = g * 8;
  const int g4   = g * 4;

  // XCD-bijective swizzle: XCDs 0-3 -> batch 0, XCDs 4-7 -> batch 1
  const int raw = blockIdx.x;            // 256
  const int xcd = raw & 7;
  const int b   = xcd >> 2;
  const int qt0 = ((raw >> 3) * 4 + (xcd & 3)) * 32;

  const __bf16* qt = reinterpret_cast<const __bf16*>(ws8 + QT_OFF);
  const __bf16* kt = reinterpret_cast<const __bf16*>(ws8 + KT_OFF);
  const unsigned char* vp = ws8 + VP_OFF;

  f32x4 qfrag[2];
#pragma unroll
  for (int qf = 0; qf < 2; ++qf)
    qfrag[qf] = *reinterpret_cast<const f32x4*>(
        qt + (size_t)(b * 4096 + qt0 + qf * 16 + cq) * 32 + g8);

  const f32x4 zero4 = {0.f, 0.f, 0.f, 0.f};
  f32x4 acc[8][2];
#pragma unroll
  for (int ct = 0; ct < 8; ++ct) { acc[ct][0] = zero4; acc[ct][1] = zero4; }
  float m0 = -1e30f, m1 = -1e30f, l0 = 0.f, l1 = 0.f;

  unsigned char* psw0 = &ps[w][cq * 72];
  unsigned char* psw1 = &ps[w][(16 + cq) * 72];
  const __bf16* kbase = kt + (size_t)(b * 4096 + cq) * 32 + g8;
  const unsigned char* vbase = vp + (size_t)b * 524288 + lane * 8;

  const int jt_base = w * 8;             // wave covers j-tiles [w*8, w*8+8)

  f32x4 kf[4];
#pragma unroll
  for (int s = 0; s < 4; ++s)
    kf[s] = *reinterpret_cast<const f32x4*>(
        kbase + (size_t)(jt_base * 64 + s * 16) * 32);

#pragma unroll 1
  for (int tile = 0; tile < 8; ++tile) {
    const int jt = jt_base + tile;
    const int jn = jt_base + ((tile + 1) & 7);

    // ---- issue all 16 packed-V (8B) loads + 4 next-K loads ----
    long vf[2][8];
#pragma unroll
    for (int cn = 0; cn < 2; ++cn)
#pragma unroll
      for (int ct = 0; ct < 8; ++ct)
        vf[cn][ct] = *reinterpret_cast<const long*>(
            vbase + ((((size_t)jt * 8 + ct) * 2 + cn) << 9));
    f32x4 kn[4];
#pragma unroll
    for (int s = 0; s < 4; ++s)
      kn[s] = *reinterpret_cast<const f32x4*>(
          kbase + (size_t)(jn * 64 + s * 16) * 32);

    // ---- QK^T (bf16): lane holds S^T[j=jt*64+16s+g4+v][q=qf*16+cq] ----
    f32x4 sf[4][2];
#pragma unroll
    for (int s = 0; s < 4; ++s) {
      sf[s][0] = mfma16(kf[s], qfrag[0], zero4);
      sf[s][1] = mfma16(kf[s], qfrag[1], zero4);
    }

    // ---- online softmax ----
    float tmax0 = sf[0][0][0], tmax1 = sf[0][1][0];
#pragma unroll
    for (int s = 0; s < 4; ++s)
#pragma unroll
      for (int v = 0; v < 4; ++v) {
        tmax0 = fmaxf(tmax0, sf[s][0][v]);
        tmax1 = fmaxf(tmax1, sf[s][1][v]);
      }
    tmax0 = fmaxf(tmax0, __shfl_xor(tmax0, 16));
    tmax0 = fmaxf(tmax0, __shfl_xor(tmax0, 32));
    tmax1 = fmaxf(tmax1, __shfl_xor(tmax1, 16));
    tmax1 = fmaxf(tmax1, __shfl_xor(tmax1, 32));

    if (__any((tmax0 > m0 + 8.0f) || (tmax1 > m1 + 8.0f))) {   // defer-max
      float m0n = fmaxf(m0, tmax0), m1n = fmaxf(m1, tmax1);
      float sc0 = __expf(m0 - m0n), sc1 = __expf(m1 - m1n);
#pragma unroll
      for (int ct = 0; ct < 8; ++ct) { acc[ct][0] *= sc0; acc[ct][1] *= sc1; }
      l0 *= sc0; l1 *= sc1;
      m0 = m0n; m1 = m1n;
    }

    // p' = exp(s - m - ln8): bounded by e^(8-ln8) = 372 < 448 (e4m3 max).
    // psum accumulates the SAME shifted values, so O = acc'/l' is exact.
    float psum0 = 0.f, psum1 = 0.f;
#pragma unroll
    for (int s = 0; s < 4; ++s) {
      float p0[4], p1[4];
#pragma unroll
      for (int v = 0; v < 4; ++v) {
        p0[v] = fminf(__expf(sf[s][0][v] - m0 - P_LN8), 440.f);
        p1[v] = fminf(__expf(sf[s][1][v] - m1 - P_LN8), 440.f);
        psum0 += p0[v]; psum1 += p1[v];
      }
      *reinterpret_cast<unsigned*>(psw0 + s * 16 + g4) =
          f32_to_fp8x4(p0[0], p0[1], p0[2], p0[3]);
      *reinterpret_cast<unsigned*>(psw1 + s * 16 + g4) =
          f32_to_fp8x4(p1[0], p1[1], p1[2], p1[3]);
    }
    psum0 += __shfl_xor(psum0, 16); psum0 += __shfl_xor(psum0, 32);
    psum1 += __shfl_xor(psum1, 16); psum1 += __shfl_xor(psum1, 32);
    l0 += psum0; l1 += psum1;

    // ---- PV (fp8): pin loads (single batched wait), then 32 MFMAs ----
#pragma unroll
    for (int cn = 0; cn < 2; ++cn)
#pragma unroll
      for (int ct = 0; ct < 8; ++ct) pinl(vf[cn][ct]);
#pragma unroll
    for (int s = 0; s < 4; ++s) pin(kn[s]);

    __builtin_amdgcn_s_setprio(1);
#pragma unroll
    for (int cn = 0; cn < 2; ++cn) {
      long pf0 = *reinterpret_cast<const long*>(psw0 + cn * 32 + g8);
      long pf1 = *reinterpret_cast<const long*>(psw1 + cn * 32 + g8);
#pragma unroll
      for (int ct = 0; ct < 8; ++ct) {
        acc[ct][0] = __builtin_amdgcn_mfma_f32_16x16x32_fp8_fp8(
            vf[cn][ct], pf0, acc[ct][0], 0, 0, 0);
        acc[ct][1] = __builtin_amdgcn_mfma_f32_16x16x32_fp8_fp8(
            vf[cn][ct], pf1, acc[ct][1], 0, 0, 0);
      }
    }
    __builtin_amdgcn_s_setprio(0);

#pragma unroll
    for (int s = 0; s < 4; ++s) kf[s] = kn[s];
  }

  // ---- cross-wave merge (8 partials) ----
  if (lane < 16) {
    m_lds[w][cq] = m0; m_lds[w][16 + cq] = m1;
    l_lds[w][cq] = l0; l_lds[w][16 + cq] = l1;
  }
  __syncthreads();

  float mstar0 = m_lds[0][cq],      mstar1 = m_lds[0][16 + cq];
#pragma unroll
  for (int ww = 1; ww < 8; ++ww) {
    mstar0 = fmaxf(mstar0, m_lds[ww][cq]);
    mstar1 = fmaxf(mstar1, m_lds[ww][16 + cq]);
  }
  float lstar0 = 0.f, lstar1 = 0.f;
#pragma unroll
  for (int ww = 0; ww < 8; ++ww) {
    lstar0 += l_lds[ww][cq]      * __expf(m_lds[ww][cq]      - mstar0);
    lstar1 += l_lds[ww][16 + cq] * __expf(m_lds[ww][16 + cq] - mstar1);
  }
  float sc0 = __expf(m0 - mstar0), sc1 = __expf(m1 - mstar1);
  if (w == 0 && lane < 16) { lstar_lds[cq] = lstar0; lstar_lds[16 + cq] = lstar1; }

  const int r = w & 3;
  if (w < 4) {
#pragma unroll
    for (int ct = 0; ct < 8; ++ct)
#pragma unroll
      for (int v = 0; v < 4; ++v) {
        o_lds[r][ct * 16 + g4 + v][cq]      = acc[ct][0][v] * sc0;
        o_lds[r][ct * 16 + g4 + v][16 + cq] = acc[ct][1][v] * sc1;
      }
  }
  __syncthreads();
  if (w >= 4) {
#pragma unroll
    for (int ct = 0; ct < 8; ++ct)
#pragma unroll
      for (int v = 0; v < 4; ++v) {
        o_lds[r][ct * 16 + g4 + v][cq]      += acc[ct][0][v] * sc0;
        o_lds[r][ct * 16 + g4 + v][16 + cq] += acc[ct][1][v] * sc1;
      }
  }
  __syncthreads();

  // ---- epilogue: out = gamma * O/l + x ----
  const float g0 = gamma_p[0];
  for (int idx = t; idx < 128 * 32; idx += 512) {
    int c = idx >> 5, qq = idx & 31;
    float o = (o_lds[0][c][qq] + o_lds[1][c][qq] +
               o_lds[2][c][qq] + o_lds[3][c][qq]) / lstar_lds[qq];
    size_t addr = (size_t)(b * 128 + c) * N_VOX + qt0 + qq;
    out[addr] = fmaf(g0, o, x[addr]);
  }
}

// ---------------------------------------------------------------------------
extern "C" void kernel_launch(void* const* d_in, const int* in_sizes, int n_in,
                              void* d_out, int out_size, void* d_ws, size_t ws_size,
                              hipStream_t stream) {
  const float* x     = (const float*)d_in[0];
  const float* wq    = (const float*)d_in[1];
  const float* bq    = (const float*)d_in[2];
  const float* wk    = (const float*)d_in[3];
  const float* bk    = (const float*)d_in[4];
  const float* wv    = (const float*)d_in[5];
  const float* bv    = (const float*)d_in[6];
  const float* gamma = (const float*)d_in[7];
  float* out = (float*)d_out;
  unsigned char* ws8 = (unsigned char*)d_ws;   // 2 MB

  proj_kernel<<<256, 256, 0, stream>>>(x, wq, bq, wk, bk, wv, bv, ws8);
  attn_kernel<<<256, 512, 0, stream>>>(ws8, x, gamma, out);
}